// Round 7
// baseline (2876.573 us; speedup 1.0000x reference)
//
#include <hip/hip_runtime.h>
#include <cstdint>

// Autoregressive LSTM, MI355X. 512 blocks x 512 threads, ONE batch row per block,
// 2 independent blocks/CU (4 waves/SIMD). Weight placement tuned for the 128-VGPR
// cap at 4 waves/SIMD: W_hh (64 u32 f16-pairs) + W_den (8 u32) pinned in VGPRs
// (72 regs), W_ih in LDS (64KB, XOR-swizzled uint4 rows -> conflict-free wave
// reads). Builtin fdot2 + __shfl paths (bisect-proven). 2 barriers/step.

#define T_SEQ 1024
#define N_F   64
#define N_H   128

typedef _Float16 h2f __attribute__((ext_vector_type(2)));

__device__ __forceinline__ float sigf(float x) {
    return __builtin_amdgcn_rcpf(1.f + __expf(-x));
}
__device__ __forceinline__ float tanh_fast(float x) {
    return 1.f - 2.f * __builtin_amdgcn_rcpf(1.f + __expf(2.f * x));
}

#if __has_builtin(__builtin_amdgcn_fdot2)
__device__ __forceinline__ float fdot2(uint32_t a, uint32_t b, float c) {
    return __builtin_amdgcn_fdot2(__builtin_bit_cast(h2f, a),
                                  __builtin_bit_cast(h2f, b), c, false);
}
#else
__device__ __forceinline__ float fdot2(uint32_t a, uint32_t b, float c) {
    h2f av = __builtin_bit_cast(h2f, a), bv = __builtin_bit_cast(h2f, b);
    return fmaf((float)av.x, (float)bv.x, fmaf((float)av.y, (float)bv.y, c));
}
#endif

__device__ __forceinline__ uint32_t packh2(float a, float b) {
    h2f v; v.x = (_Float16)a; v.y = (_Float16)b;
    return __builtin_bit_cast(uint32_t, v);
}

__global__ __launch_bounds__(512, 4)
void lstm_autoreg(const float* __restrict__ x,
                  const int*   __restrict__ avail,
                  const int*   __restrict__ pred,
                  const float* __restrict__ W_ih,
                  const float* __restrict__ W_hh,
                  const float* __restrict__ b_ih,
                  const float* __restrict__ b_hh,
                  const float* __restrict__ W_den,
                  const float* __restrict__ b_den,
                  const float* __restrict__ init_ch,
                  float*       __restrict__ out)
{
    __shared__ __align__(16) uint4    wihL[512 * 8];   // W_ih f16 pairs, swizzled, 64KB
    __shared__ __align__(16) uint32_t xT[32][32];      // [tmod][fpair] f16x2, 4KB
    __shared__ __align__(16) float    obuf[N_F][20];   // out staging, 5KB
    __shared__ __align__(16) uint32_t h2buf[2][64];    // [buf][jpair] f16x2
    __shared__ __align__(16) uint32_t pv2[32];         // prev out f16 pairs
    __shared__ int red[8];

    const int tid  = threadIdx.x;
    const int lane = tid & 63;
    const int r    = blockIdx.x;          // one batch row per block

    // ---- max_idx = min(max(predict_len), T): 512 threads == BATCH ----
    int pv = pred[tid];
    #pragma unroll
    for (int m = 1; m < 64; m <<= 1) pv = max(pv, __shfl_xor(pv, m));
    if (lane == 0) red[tid >> 6] = pv;
    __syncthreads();
    int max_idx = red[0];
    #pragma unroll
    for (int w = 1; w < 8; ++w) max_idx = max(max_idx, red[w]);
    if (max_idx > T_SEQ) max_idx = T_SEQ;

    // ---- role indices ----
    const int gt  = tid & 3;         // gate type (i,f,g,o)
    const int j   = tid >> 2;        // hidden unit [0,128)
    const int g   = gt * N_H + j;    // weight row [0,512)
    const int of  = tid >> 3;        // dense feature [0,64)
    const int oc  = tid & 7;         // dense K-chunk [0,8)
    const int swz = tid & 7;         // XOR swizzle key for wihL

    // ---- W_hh + W_den -> packed f16 in VGPRs (72 regs, pinned) ----
    uint32_t whh[64], wdn[8];
    {
        const float* q = W_hh + g * N_H;
        #pragma unroll
        for (int i = 0; i < 64; ++i) whh[i] = packh2(q[2*i], q[2*i+1]);
        const float* rr = W_den + of * N_H + oc * 16;
        #pragma unroll
        for (int i = 0; i < 8; ++i) wdn[i] = packh2(rr[2*i], rr[2*i+1]);
    }
    #pragma unroll
    for (int i = 0; i < 64; ++i) asm volatile("" : "+v"(whh[i]));
    #pragma unroll
    for (int i = 0; i < 8; ++i)  asm volatile("" : "+v"(wdn[i]));

    // ---- W_ih -> LDS, f16 pairs, XOR-swizzled uint4 slots ----
    {
        const float* p = W_ih + g * N_F;
        #pragma unroll
        for (int kk = 0; kk < 8; ++kk) {
            uint4 v;
            v.x = packh2(p[8*kk + 0], p[8*kk + 1]);
            v.y = packh2(p[8*kk + 2], p[8*kk + 3]);
            v.z = packh2(p[8*kk + 4], p[8*kk + 5]);
            v.w = packh2(p[8*kk + 6], p[8*kk + 7]);
            wihL[g * 8 + (kk ^ swz)] = v;
        }
    }

    const float bacc = b_ih[g] + b_hh[g];
    const float bden = b_den[of];
    const int av = avail[r], pr = pred[r];

    // ---- state init ----
    float c = init_ch[j];                               // c0 = init_ch[:H]
    if (tid < 64)
        h2buf[0][tid] = packh2(init_ch[N_H + 2*tid], init_ch[N_H + 2*tid + 1]);
    __syncthreads();

    for (int t = 0; t < T_SEQ; ++t) {
        // ---- stage 32 timesteps of x, transposed, f32 -> f16 ----
        if ((t & 31) == 0) {
            int tq = tid & 7, f = tid >> 3;             // 512 float4 total
            const float4 v = *(const float4*)
                (x + ((size_t)r * N_F + f) * T_SEQ + t + tq * 4);
            _Float16* dst = (_Float16*)&xT[0][0];
            dst[(tq*4+0)*64 + f] = (_Float16)v.x;
            dst[(tq*4+1)*64 + f] = (_Float16)v.y;
            dst[(tq*4+2)*64 + f] = (_Float16)v.z;
            dst[(tq*4+3)*64 + f] = (_Float16)v.w;
            __syncthreads();
        }
        const int rb = t & 1, wb = rb ^ 1;
        const int tm = t & 31;

        // ---- phase A: gates + cell ----
        const bool fb = (t >= av) & (t < pr) & (t > 0);
        const uint4* xs4 = fb ? (const uint4*)pv2 : (const uint4*)&xT[tm][0];

        float ax0 = bacc, ax1 = 0.f;
        #pragma unroll
        for (int kk = 0; kk < 8; ++kk) {
            uint4 w  = wihL[g * 8 + (kk ^ swz)];
            uint4 xv = xs4[kk];
            ax0 = fdot2(w.x, xv.x, ax0);
            ax1 = fdot2(w.y, xv.y, ax1);
            ax0 = fdot2(w.z, xv.z, ax0);
            ax1 = fdot2(w.w, xv.w, ax1);
        }
        const uint4* hb4 = (const uint4*)h2buf[rb];
        float bh0 = 0.f, bh1 = 0.f, bh2 = 0.f, bh3 = 0.f;
        #pragma unroll
        for (int kk = 0; kk < 16; ++kk) {
            uint4 h4 = hb4[kk];
            bh0 = fdot2(whh[4*kk + 0], h4.x, bh0);
            bh1 = fdot2(whh[4*kk + 1], h4.y, bh1);
            bh2 = fdot2(whh[4*kk + 2], h4.z, bh2);
            bh3 = fdot2(whh[4*kk + 3], h4.w, bh3);
        }
        float g0 = (ax0 + ax1) + ((bh0 + bh1) + (bh2 + bh3));

        // each lane activates its OWN gate, then quad-broadcast activated values
        float act = (gt == 2) ? tanh_fast(g0) : sigf(g0);
        const int qb = lane & ~3;
        float ai = __shfl(act, qb + 0), af = __shfl(act, qb + 1);
        float ag = __shfl(act, qb + 2), ao = __shfl(act, qb + 3);

        c = af * c + ai * ag;
        float h = ao * tanh_fast(c);
        if (gt == 0)
            ((_Float16*)&h2buf[wb][0])[j] = (_Float16)h;
        __syncthreads();

        // ---- phase B: dense out (8 threads per feature) ----
        const uint4* hq = (const uint4*)&h2buf[wb][oc * 8];
        float d0 = 0.f, d1 = 0.f;
        {
            uint4 a = hq[0], b = hq[1];
            d0 = fdot2(wdn[0], a.x, d0); d1 = fdot2(wdn[1], a.y, d1);
            d0 = fdot2(wdn[2], a.z, d0); d1 = fdot2(wdn[3], a.w, d1);
            d0 = fdot2(wdn[4], b.x, d0); d1 = fdot2(wdn[5], b.y, d1);
            d0 = fdot2(wdn[6], b.z, d0); d1 = fdot2(wdn[7], b.w, d1);
        }
        float d = d0 + d1;
        d += __shfl_xor(d, 1);
        d += __shfl_xor(d, 2);
        d += __shfl_xor(d, 4);
        if (oc == 0) {
            float o = d + bden;
            ((_Float16*)pv2)[of] = (_Float16)o;       // feedback (unmasked)
            obuf[of][t & 15] = (t < max_idx) ? o : 0.f;
        }

        // ---- flush outputs, coalesced, every 16 steps ----
        if ((t & 15) == 15) {
            __syncthreads();
            int f = tid >> 3, tq = tid & 7;           // 512 float2, 1 per thread
            float2 v = *(const float2*)&obuf[f][tq * 2];
            *(float2*)(out + ((size_t)r * N_F + f) * T_SEQ + (t & ~15) + tq * 2) = v;
        }
        __syncthreads();
    }
}

extern "C" void kernel_launch(void* const* d_in, const int* in_sizes, int n_in,
                              void* d_out, int out_size, void* d_ws, size_t ws_size,
                              hipStream_t stream) {
    const float* x      = (const float*)d_in[0];
    const int*   avail  = (const int*)  d_in[1];
    const int*   pred   = (const int*)  d_in[2];
    const float* W_ih   = (const float*)d_in[3];
    const float* W_hh   = (const float*)d_in[4];
    const float* b_ih   = (const float*)d_in[5];
    const float* b_hh   = (const float*)d_in[6];
    const float* W_den  = (const float*)d_in[7];
    const float* b_den  = (const float*)d_in[8];
    const float* initch = (const float*)d_in[9];
    float* out = (float*)d_out;

    hipLaunchKernelGGL(lstm_autoreg, dim3(512), dim3(512), 0, stream,
                       x, avail, pred, W_ih, W_hh, b_ih, b_hh, W_den, b_den,
                       initch, out);
}